// Round 2
// baseline (476.577 us; speedup 1.0000x reference)
//
#include <hip/hip_runtime.h>
#include <hip/hip_bf16.h>

typedef unsigned short u16;
typedef __attribute__((ext_vector_type(8))) short short8;   // 8 x bf16 bits = 4 VGPRs
typedef __attribute__((ext_vector_type(4))) float f32x4;

#define B_    4
#define L_    8192
#define C_    256
#define BL_   (B_*L_)
#define BLC_  (BL_*C_)
#define FFN_  2048
#define KCAT_ 512
#define EPS_  1e-5f

__device__ __forceinline__ float bf2f(u16 v) {
  union { unsigned int u; float f; } x; x.u = ((unsigned int)v) << 16; return x.f;
}
__device__ __forceinline__ u16 f2bf(float f) {
  union { float f; unsigned int u; } x; x.f = f;
  unsigned int lsb = (x.u >> 16) & 1u;
  return (u16)((x.u + 0x7fffu + lsb) >> 16);
}

// ---------------------------------------------------------------------------
// Workhorse GEMM: C[m,n] = act( sum_k A[m,k] * Bt[n,k] + bias[n] )
// A: row-major M x K bf16 (virtual concat: k<KA from A0, else A1)
// Bt: row-major N x K bf16 (ldb == K). m97 structure: 128x128 tile, BK=32,
// 4 waves, global_load_lds width 16, mfma_f32_16x16x32_bf16.
// SPLITK=1 -> fp32 atomicAdd into Cf.
// ---------------------------------------------------------------------------
template<int ACT, int SPLITK>
__launch_bounds__(256, 2)
__global__ void gemm_abt(const u16* __restrict__ A0, const u16* __restrict__ A1,
                         int KA, int lda,
                         const u16* __restrict__ Bt,
                         const float* __restrict__ bias,
                         u16* __restrict__ Cb, float* __restrict__ Cf,
                         int M, int N, int K,
                         long sAb, long sBb, long sCb)
{
  __shared__ __align__(16) u16 As[128 * 32];
  __shared__ __align__(16) u16 Bs[128 * 32];

  const int ntiles = N >> 7;
  const int tile = blockIdx.x;
  const int mt0 = (tile / ntiles) << 7;
  const int nt0 = (tile % ntiles) << 7;
  const int kchunk = K / (int)gridDim.y;
  const int k0beg = blockIdx.y * kchunk;
  const int k0end = k0beg + kchunk;
  const int bz = blockIdx.z;
  A0 += (long)bz * sAb;  A1 += (long)bz * sAb;  Bt += (long)bz * sBb;

  const int tid  = threadIdx.x;
  const int wave = tid >> 6, lane = tid & 63;
  const int srow = lane >> 2;         // staging row within 16-row chunk
  const int scol = (lane & 3) * 8;    // staging col (elements, 8 bf16 = 16B)
  const int frow = lane & 15;         // fragment m/n index
  const int fq   = lane >> 4;         // fragment quad

  f32x4 zero = {0.f, 0.f, 0.f, 0.f};
  f32x4 acc[4][4];
#pragma unroll
  for (int i = 0; i < 4; i++)
#pragma unroll
    for (int j = 0; j < 4; j++) acc[i][j] = zero;

  const int wm = (wave & 1) * 64, wn = (wave >> 1) * 64;

  for (int k0 = k0beg; k0 < k0end; k0 += 32) {
    __syncthreads();
    const u16* Asrc = (k0 < KA) ? (A0 + k0) : (A1 + (k0 - KA));
#pragma unroll
    for (int i = 0; i < 2; i++) {
      const int chunk = i * 4 + wave;  // 0..7, 16 rows each
      const u16* ga = Asrc + (long)(mt0 + chunk * 16 + srow) * lda + scol;
      __builtin_amdgcn_global_load_lds(
          (const __attribute__((address_space(1))) unsigned int*)ga,
          (__attribute__((address_space(3))) unsigned int*)&As[chunk * 16 * 32],
          16, 0, 0);
      const u16* gb = Bt + (long)(nt0 + chunk * 16 + srow) * K + (k0 + scol);
      __builtin_amdgcn_global_load_lds(
          (const __attribute__((address_space(1))) unsigned int*)gb,
          (__attribute__((address_space(3))) unsigned int*)&Bs[chunk * 16 * 32],
          16, 0, 0);
    }
    __syncthreads();

    short8 af[4], bf[4];
#pragma unroll
    for (int t = 0; t < 4; t++)
      af[t] = *(const short8*)&As[(wm + t * 16 + frow) * 32 + fq * 8];
#pragma unroll
    for (int t = 0; t < 4; t++)
      bf[t] = *(const short8*)&Bs[(wn + t * 16 + frow) * 32 + fq * 8];
#pragma unroll
    for (int mt = 0; mt < 4; mt++)
#pragma unroll
      for (int nt = 0; nt < 4; nt++)
        acc[mt][nt] = __builtin_amdgcn_mfma_f32_16x16x32_bf16(af[mt], bf[nt], acc[mt][nt], 0, 0, 0);
  }

  if (SPLITK) {
    float* Cp = Cf + (long)bz * sCb;
#pragma unroll
    for (int mt = 0; mt < 4; mt++)
#pragma unroll
      for (int r = 0; r < 4; r++) {
        const int row = mt0 + wm + mt * 16 + fq * 4 + r;
#pragma unroll
        for (int nt = 0; nt < 4; nt++) {
          const int col = nt0 + wn + nt * 16 + frow;
          atomicAdd(&Cp[(long)row * N + col], acc[mt][nt][r]);
        }
      }
  } else {
    u16* Cp = Cb + (long)bz * sCb;
    float bv[4];
#pragma unroll
    for (int nt = 0; nt < 4; nt++)
      bv[nt] = bias ? bias[nt0 + wn + nt * 16 + frow] : 0.f;
#pragma unroll
    for (int mt = 0; mt < 4; mt++)
#pragma unroll
      for (int r = 0; r < 4; r++) {
        const int row = mt0 + wm + mt * 16 + fq * 4 + r;
#pragma unroll
        for (int nt = 0; nt < 4; nt++) {
          const int col = nt0 + wn + nt * 16 + frow;
          float v = acc[mt][nt][r] + bv[nt];
          if (ACT == 1) v = 0.5f * v * (1.f + erff(v * 0.70710678118654752f)); // exact GELU
          Cp[(long)row * N + col] = f2bf(v);
        }
      }
  }
}

// ---------------------------------------------------------------------------
// bf16 (R x Cc) -> (Cc x R) transpose, per blockIdx.z batch. Block (32,8).
// ---------------------------------------------------------------------------
__global__ void transpose2d(const u16* __restrict__ in, u16* __restrict__ out,
                            int R, int Cc, long sIb, long sOb)
{
  __shared__ u16 t[32][33];
  const int bx = blockIdx.x * 32;  // input col base
  const int by = blockIdx.y * 32;  // input row base
  in  += (long)blockIdx.z * sIb;
  out += (long)blockIdx.z * sOb;
  const int tx = threadIdx.x, ty = threadIdx.y;
#pragma unroll
  for (int i = ty; i < 32; i += 8)
    t[i][tx] = in[(long)(by + i) * Cc + bx + tx];
  __syncthreads();
#pragma unroll
  for (int i = ty; i < 32; i += 8)
    out[(long)(bx + i) * R + by + tx] = t[tx][i];
}

// fp32 (R x Cc) -> bf16 (Cc x R) transpose (weight packing). Block (32,8).
__global__ void transpose_f2b(const float* __restrict__ in, u16* __restrict__ out,
                              int R, int Cc)
{
  __shared__ u16 t[32][33];
  const int bx = blockIdx.x * 32;
  const int by = blockIdx.y * 32;
  const int tx = threadIdx.x, ty = threadIdx.y;
#pragma unroll
  for (int i = ty; i < 32; i += 8)
    t[i][tx] = f2bf(in[(long)(by + i) * Cc + bx + tx]);
  __syncthreads();
#pragma unroll
  for (int i = ty; i < 32; i += 8)
    out[(long)(bx + i) * R + by + tx] = t[tx][i];
}

// fp32 -> bf16 elementwise (n divisible by 4)
__global__ void cast_f2b(const float* __restrict__ in, u16* __restrict__ out, int n)
{
  int i = (blockIdx.x * 256 + threadIdx.x) * 4;
  if (i < n) {
    float4 v = *(const float4*)(in + i);
    ushort4 o; o.x = f2bf(v.x); o.y = f2bf(v.y); o.z = f2bf(v.z); o.w = f2bf(v.w);
    *(ushort4*)(out + i) = o;
  }
}

// ---------------------------------------------------------------------------
// In-place softmax over each row (length rowlen), bf16. One block per row.
// ---------------------------------------------------------------------------
__global__ void softmax_rows(u16* __restrict__ data, int rowlen)
{
  const long base = (long)blockIdx.x * rowlen;
  const int tid = threadIdx.x, wave = tid >> 6, lane = tid & 63;
  __shared__ float red[4];

  float m = -3.4e38f;
  for (int i = tid; i < rowlen; i += 256) m = fmaxf(m, bf2f(data[base + i]));
#pragma unroll
  for (int off = 32; off; off >>= 1) m = fmaxf(m, __shfl_xor(m, off, 64));
  if (lane == 0) red[wave] = m;
  __syncthreads();
  m = fmaxf(fmaxf(red[0], red[1]), fmaxf(red[2], red[3]));
  __syncthreads();

  float s = 0.f;
  for (int i = tid; i < rowlen; i += 256) s += expf(bf2f(data[base + i]) - m);
#pragma unroll
  for (int off = 32; off; off >>= 1) s += __shfl_xor(s, off, 64);
  if (lane == 0) red[wave] = s;
  __syncthreads();
  const float inv = 1.f / (red[0] + red[1] + red[2] + red[3]);
  for (int i = tid; i < rowlen; i += 256)
    data[base + i] = f2bf(expf(bf2f(data[base + i]) - m) * inv);
}

// ---------------------------------------------------------------------------
// LayerNorm over rows of length 256 (bf16 x, fp32 gamma/beta).
// OUTF=0: bf16 out. OUTF=1: fp32 out with residual add of fp32 src.
// One wave per row, 4 elems/lane.
// ---------------------------------------------------------------------------
template<int OUTF>
__global__ void layernorm_rows(const u16* __restrict__ x,
                               const float* __restrict__ gamma,
                               const float* __restrict__ beta,
                               const float* __restrict__ src,
                               void* __restrict__ outv)
{
  const int wave = threadIdx.x >> 6, lane = threadIdx.x & 63;
  const long row = (long)blockIdx.x * 4 + wave;
  ushort4 raw = ((const ushort4*)(x + row * C_))[lane];
  float v0 = bf2f(raw.x), v1 = bf2f(raw.y), v2 = bf2f(raw.z), v3 = bf2f(raw.w);
  float s = v0 + v1 + v2 + v3;
  float q = v0 * v0 + v1 * v1 + v2 * v2 + v3 * v3;
#pragma unroll
  for (int off = 32; off; off >>= 1) {
    s += __shfl_xor(s, off, 64);
    q += __shfl_xor(q, off, 64);
  }
  const float mu  = s * (1.f / C_);
  const float var = q * (1.f / C_) - mu * mu;
  const float rs  = 1.f / sqrtf(var + EPS_);
  float4 gr = ((const float4*)gamma)[lane];
  float4 br = ((const float4*)beta)[lane];
  float o0 = (v0 - mu) * rs * gr.x + br.x;
  float o1 = (v1 - mu) * rs * gr.y + br.y;
  float o2 = (v2 - mu) * rs * gr.z + br.z;
  float o3 = (v3 - mu) * rs * gr.w + br.w;
  if (OUTF) {
    float4 sr = ((const float4*)(src + row * C_))[lane];
    float4 ow; ow.x = o0 + sr.x; ow.y = o1 + sr.y; ow.z = o2 + sr.z; ow.w = o3 + sr.w;
    ((float4*)((float*)outv + row * C_))[lane] = ow;
  } else {
    ushort4 ow; ow.x = f2bf(o0); ow.y = f2bf(o1); ow.z = f2bf(o2); ow.w = f2bf(o3);
    ((ushort4*)((u16*)outv + row * C_))[lane] = ow;
  }
}

__global__ void zero_f32(float* __restrict__ p, int n) {
  int i = blockIdx.x * 256 + threadIdx.x;
  if (i < n) p[i] = 0.f;
}
__global__ void f32_to_bf16_k(const float* __restrict__ in, u16* __restrict__ out, int n) {
  int i = blockIdx.x * 256 + threadIdx.x;
  if (i < n) out[i] = f2bf(in[i]);
}

// ---------------------------------------------------------------------------
extern "C" void kernel_launch(void* const* d_in, const int* in_sizes, int n_in,
                              void* d_out, int out_size, void* d_ws, size_t ws_size,
                              hipStream_t stream)
{
  const float* source = (const float*)d_in[0];
  const float* target = (const float*)d_in[1];
  const float* Wq     = (const float*)d_in[2];
  const float* Wk     = (const float*)d_in[3];
  const float* Wv     = (const float*)d_in[4];
  const float* Wl     = (const float*)d_in[5];
  const float* gamma1 = (const float*)d_in[6];
  const float* beta1  = (const float*)d_in[7];
  const float* W1     = (const float*)d_in[8];
  const float* b1     = (const float*)d_in[9];
  const float* W2     = (const float*)d_in[10];
  const float* b2     = (const float*)d_in[11];
  const float* gamma2 = (const float*)d_in[12];
  const float* beta2  = (const float*)d_in[13];
  (void)in_sizes; (void)n_in; (void)out_size;

  char* ws = (char*)d_ws;
  size_t off = 0;
  auto take = [&](size_t bytes) -> char* {
    char* p = ws + off; off += (bytes + 255) & ~(size_t)255; return p;
  };
  u16*   WqT  = (u16*)take((size_t)C_ * C_ * 2);
  u16*   WkT  = (u16*)take((size_t)C_ * C_ * 2);
  u16*   WvT  = (u16*)take((size_t)C_ * C_ * 2);
  u16*   WlT  = (u16*)take((size_t)C_ * C_ * 2);
  u16*   W1T  = (u16*)take((size_t)FFN_ * KCAT_ * 2);
  u16*   W2T  = (u16*)take((size_t)C_ * FFN_ * 2);
  float* ctxf = (float*)take((size_t)B_ * C_ * C_ * 4);
  u16*   ctxb = (u16*)take((size_t)B_ * C_ * C_ * 2);
  u16*   srcB = (u16*)take((size_t)BLC_ * 2);   // bf16 source (FFN1 A0)
  u16*   tgtB = (u16*)take((size_t)BLC_ * 2);   // bf16 target
  u16*   bufA = (u16*)take((size_t)BLC_ * 2);   // q   -> attn
  u16*   bufB = (u16*)take((size_t)BLC_ * 2);   // k   -> msg_pre
  u16*   bufC = (u16*)take((size_t)BLC_ * 2);   // v
  u16*   bufD = (u16*)take((size_t)BLC_ * 2);   // qT  -> message
  u16*   bufE = (u16*)take((size_t)BLC_ * 2);   // kT(softmax) -> out_pre

  // hidden chunking ladder: fit (BL_/nchunk) x FFN_ bf16 in remaining ws
  int nchunk = 1;
  while (nchunk < 8 &&
         off + ((size_t)BL_ / nchunk) * FFN_ * 2 + 4096 > ws_size)
    nchunk <<= 1;
  const int Mc = BL_ / nchunk;
  u16* hidden = (u16*)take((size_t)Mc * FFN_ * 2);

  dim3 tb(32, 8);
  cast_f2b<<<BLC_ / 4 / 256, 256, 0, stream>>>(source, srcB, BLC_);
  cast_f2b<<<BLC_ / 4 / 256, 256, 0, stream>>>(target, tgtB, BLC_);
  transpose_f2b<<<dim3(C_/32,  C_/32),  tb, 0, stream>>>(Wq, WqT, C_,   C_);
  transpose_f2b<<<dim3(C_/32,  C_/32),  tb, 0, stream>>>(Wk, WkT, C_,   C_);
  transpose_f2b<<<dim3(C_/32,  C_/32),  tb, 0, stream>>>(Wv, WvT, C_,   C_);
  transpose_f2b<<<dim3(C_/32,  C_/32),  tb, 0, stream>>>(Wl, WlT, C_,   C_);
  transpose_f2b<<<dim3(FFN_/32, KCAT_/32), tb, 0, stream>>>(W1, W1T, KCAT_, FFN_);
  transpose_f2b<<<dim3(C_/32,  FFN_/32), tb, 0, stream>>>(W2, W2T, FFN_, C_);
  zero_f32<<<(B_*C_*C_ + 255)/256, 256, 0, stream>>>(ctxf, B_*C_*C_);

  // Projections
  gemm_abt<0,0><<<dim3((BL_/128)*(C_/128)), 256, 0, stream>>>(
      srcB, srcB, C_, C_, WqT, nullptr, bufA, nullptr, BL_, C_, C_, 0, 0, 0);
  gemm_abt<0,0><<<dim3((BL_/128)*(C_/128)), 256, 0, stream>>>(
      tgtB, tgtB, C_, C_, WkT, nullptr, bufB, nullptr, BL_, C_, C_, 0, 0, 0);
  gemm_abt<0,0><<<dim3((BL_/128)*(C_/128)), 256, 0, stream>>>(
      tgtB, tgtB, C_, C_, WvT, nullptr, bufC, nullptr, BL_, C_, C_, 0, 0, 0);

  // q,k -> (B, C, L); token-softmax = row softmax on kT
  transpose2d<<<dim3(C_/32, L_/32, B_), tb, 0, stream>>>(bufA, bufD, L_, C_, (long)L_*C_, (long)L_*C_);
  transpose2d<<<dim3(C_/32, L_/32, B_), tb, 0, stream>>>(bufB, bufE, L_, C_, (long)L_*C_, (long)L_*C_);
  softmax_rows<<<B_*C_, 256, 0, stream>>>(bufE, L_);

  // ctx[d,e] = sum_n qT[d,n] * ksmT[e,n]  (split-K over tokens, fp32 atomics)
  gemm_abt<0,1><<<dim3((C_/128)*(C_/128), 16, B_), 256, 0, stream>>>(
      bufD, bufD, L_, L_, bufE, nullptr, nullptr, ctxf, C_, C_, L_,
      (long)C_*L_, (long)C_*L_, (long)C_*C_);
  f32_to_bf16_k<<<(B_*C_*C_ + 255)/256, 256, 0, stream>>>(ctxf, ctxb, B_*C_*C_);

  // attn[n,d] = sum_e v[n,e] * ctx[d,e]
  gemm_abt<0,0><<<dim3((L_/128)*(C_/128), 1, B_), 256, 0, stream>>>(
      bufC, bufC, C_, C_, ctxb, nullptr, bufA, nullptr, L_, C_, C_,
      (long)L_*C_, (long)C_*C_, (long)L_*C_);

  // msg_pre = attn @ Wl
  gemm_abt<0,0><<<dim3((BL_/128)*(C_/128)), 256, 0, stream>>>(
      bufA, bufA, C_, C_, WlT, nullptr, bufB, nullptr, BL_, C_, C_, 0, 0, 0);

  // message = LN1(msg_pre)  (bf16 out)
  layernorm_rows<0><<<BL_/4, 256, 0, stream>>>(bufB, gamma1, beta1, nullptr, bufD);

  // FFN (chunked over M): hidden = gelu([src|msg]@W1+b1); out_pre = hidden@W2+b2
  for (int ch = 0; ch < nchunk; ch++) {
    const long moff = (long)ch * Mc;
    gemm_abt<1,0><<<dim3((Mc/128)*(FFN_/128)), 256, 0, stream>>>(
        srcB + moff * C_, bufD + moff * C_, C_, C_, W1T, b1, hidden, nullptr,
        Mc, FFN_, KCAT_, 0, 0, 0);
    gemm_abt<0,0><<<dim3((Mc/128)*(C_/128)), 256, 0, stream>>>(
        hidden, hidden, FFN_, FFN_, W2T, b2, bufE + moff * C_, nullptr,
        Mc, C_, FFN_, 0, 0, 0);
  }

  // out = source + LN2(out_pre)  (fp32 out)
  layernorm_rows<1><<<BL_/4, 256, 0, stream>>>(bufE, gamma2, beta2, source, d_out);
}

// Round 3
// 420.283 us; speedup vs baseline: 1.1339x; 1.1339x over previous
//
#include <hip/hip_runtime.h>
#include <hip/hip_bf16.h>

typedef unsigned short u16;
typedef __attribute__((ext_vector_type(8))) short short8;   // 8 x bf16 bits = 4 VGPRs
typedef __attribute__((ext_vector_type(4))) float f32x4;

#define B_    4
#define L_    8192
#define C_    256
#define BL_   (B_*L_)
#define BLC_  (BL_*C_)
#define FFN_  2048
#define KCAT_ 512
#define EPS_  1e-5f

__device__ __forceinline__ float bf2f(u16 v) {
  union { unsigned int u; float f; } x; x.u = ((unsigned int)v) << 16; return x.f;
}
__device__ __forceinline__ u16 f2bf(float f) {
  union { float f; unsigned int u; } x; x.f = f;
  unsigned int lsb = (x.u >> 16) & 1u;
  return (u16)((x.u + 0x7fffu + lsb) >> 16);
}
// exact-GELU via A&S 7.1.26 erf (max abs err 1.5e-7), branchless
__device__ __forceinline__ float gelu_f(float x) {
  float z = fabsf(x) * 0.70710678118654752f;
  float t = __builtin_amdgcn_rcpf(1.f + 0.3275911f * z);
  float p = ((((1.061405429f * t - 1.453152027f) * t + 1.421413741f) * t
              - 0.284496736f) * t + 0.254829592f) * t;
  float e = __expf(-z * z);
  float erfv = copysignf(1.f - p * e, x);
  return 0.5f * x * (1.f + erfv);
}

// ---------------------------------------------------------------------------
// GEMM: C[m,n] = act( sum_k A[m,k] * Bt[n,k] + bias[n] )
// MODE 0: A = A0. MODE 1: K-concat (k<SEL from A0 else A1, same lda).
// MODE 2: N-switch (nt0<SEL -> A0 else A1) for fused QKV.
// BK=64 as two 32-col LDS half-tiles; DMA column-quad XOR swizzle (q^=row&3)
// reduces fragment ds_read_b128 bank conflicts 8-way -> 4-way.
// SPLITK=1 -> fp32 atomicAdd into Cf.
// ---------------------------------------------------------------------------
template<int MODE, int ACT, int SPLITK>
__launch_bounds__(256, 2)
__global__ void gemm_abt(const u16* __restrict__ A0, const u16* __restrict__ A1,
                         int SEL, int lda,
                         const u16* __restrict__ Bt,
                         const float* __restrict__ bias,
                         u16* __restrict__ Cb, float* __restrict__ Cf,
                         int M, int N, int K,
                         long sAb, long sBb, long sCb)
{
  __shared__ __align__(16) u16 As[2 * 128 * 32];   // [half][row][32]
  __shared__ __align__(16) u16 Bs[2 * 128 * 32];

  const int ntiles = N >> 7;
  const int tile = blockIdx.x;
  const int mt0 = (tile / ntiles) << 7;
  const int nt0 = (tile % ntiles) << 7;
  const int kchunk = K / (int)gridDim.y;
  const int k0beg = blockIdx.y * kchunk;
  const int k0end = k0beg + kchunk;
  const int bz = blockIdx.z;
  A0 += (long)bz * sAb;  A1 += (long)bz * sAb;  Bt += (long)bz * sBb;

  const u16* Abase = (MODE == 2 && nt0 >= SEL) ? A1 : A0;

  const int tid  = threadIdx.x;
  const int wave = tid >> 6, lane = tid & 63;
  const int srow = lane >> 2;                 // 0..15 within 16-row chunk
  const int cq   = lane & 3;                  // column quad slot in LDS
  const int gq   = cq ^ (srow & 3);           // swizzled global column quad
  const int frow = lane & 15;                 // fragment m/n index
  const int fq   = lane >> 4;                 // fragment k-quad
  const int fqx  = (fq ^ (frow & 3)) * 8;     // swizzled LDS col for fragments

  f32x4 zero = {0.f, 0.f, 0.f, 0.f};
  f32x4 acc[4][4];
#pragma unroll
  for (int i = 0; i < 4; i++)
#pragma unroll
    for (int j = 0; j < 4; j++) acc[i][j] = zero;

  const int wm = (wave & 1) * 64, wn = (wave >> 1) * 64;

  for (int k0 = k0beg; k0 < k0end; k0 += 64) {
    __syncthreads();
    const u16* Asrc;
    int ka;
    if (MODE == 1) {
      const bool lo = (k0 < SEL);
      Asrc = lo ? A0 : A1;
      ka = lo ? k0 : (k0 - SEL);
    } else { Asrc = Abase; ka = k0; }

#pragma unroll
    for (int h = 0; h < 2; h++) {
#pragma unroll
      for (int i = 0; i < 2; i++) {
        const int chunk = i * 4 + wave;       // 0..7, 16 rows each
        const u16* ga = Asrc + (long)(mt0 + chunk * 16 + srow) * lda
                        + (ka + h * 32 + gq * 8);
        __builtin_amdgcn_global_load_lds(
            (const __attribute__((address_space(1))) unsigned int*)ga,
            (__attribute__((address_space(3))) unsigned int*)&As[h * 4096 + chunk * 16 * 32],
            16, 0, 0);
        const u16* gb = Bt + (long)(nt0 + chunk * 16 + srow) * K
                        + (k0 + h * 32 + gq * 8);
        __builtin_amdgcn_global_load_lds(
            (const __attribute__((address_space(1))) unsigned int*)gb,
            (__attribute__((address_space(3))) unsigned int*)&Bs[h * 4096 + chunk * 16 * 32],
            16, 0, 0);
      }
    }
    __syncthreads();

#pragma unroll
    for (int h = 0; h < 2; h++) {
      short8 af[4], bf[4];
#pragma unroll
      for (int t = 0; t < 4; t++)
        af[t] = *(const short8*)&As[h * 4096 + (wm + t * 16 + frow) * 32 + fqx];
#pragma unroll
      for (int t = 0; t < 4; t++)
        bf[t] = *(const short8*)&Bs[h * 4096 + (wn + t * 16 + frow) * 32 + fqx];
#pragma unroll
      for (int mt = 0; mt < 4; mt++)
#pragma unroll
        for (int nt = 0; nt < 4; nt++)
          acc[mt][nt] = __builtin_amdgcn_mfma_f32_16x16x32_bf16(af[mt], bf[nt], acc[mt][nt], 0, 0, 0);
    }
  }

  if (SPLITK) {
    float* Cp = Cf + (long)bz * sCb;
#pragma unroll
    for (int mt = 0; mt < 4; mt++)
#pragma unroll
      for (int r = 0; r < 4; r++) {
        const int row = mt0 + wm + mt * 16 + fq * 4 + r;
#pragma unroll
        for (int nt = 0; nt < 4; nt++) {
          const int col = nt0 + wn + nt * 16 + frow;
          atomicAdd(&Cp[(long)row * N + col], acc[mt][nt][r]);
        }
      }
  } else {
    u16* Cp = Cb + (long)bz * sCb;
    float bv[4];
#pragma unroll
    for (int nt = 0; nt < 4; nt++)
      bv[nt] = bias ? bias[nt0 + wn + nt * 16 + frow] : 0.f;
#pragma unroll
    for (int mt = 0; mt < 4; mt++)
#pragma unroll
      for (int r = 0; r < 4; r++) {
        const int row = mt0 + wm + mt * 16 + fq * 4 + r;
#pragma unroll
        for (int nt = 0; nt < 4; nt++) {
          const int col = nt0 + wn + nt * 16 + frow;
          float v = acc[mt][nt][r] + bv[nt];
          if (ACT == 1) v = gelu_f(v);
          Cp[(long)row * N + col] = f2bf(v);
        }
      }
  }
}

// ---------------------------------------------------------------------------
// bf16 (R x Cc slice, input row stride ldi) -> (Cc x R), per-batch z.
// ---------------------------------------------------------------------------
__global__ void transpose2d(const u16* __restrict__ in, u16* __restrict__ out,
                            int R, int Cc, int ldi, long sIb, long sOb)
{
  __shared__ u16 t[32][33];
  const int bx = blockIdx.x * 32;  // input col base
  const int by = blockIdx.y * 32;  // input row base
  in  += (long)blockIdx.z * sIb;
  out += (long)blockIdx.z * sOb;
  const int tx = threadIdx.x, ty = threadIdx.y;
#pragma unroll
  for (int i = ty; i < 32; i += 8)
    t[i][tx] = in[(long)(by + i) * ldi + bx + tx];
  __syncthreads();
#pragma unroll
  for (int i = ty; i < 32; i += 8)
    out[(long)(bx + i) * R + by + tx] = t[tx][i];
}

// fp32 (R x Cc) -> bf16 (Cc x R) weight packing.
__global__ void transpose_f2b(const float* __restrict__ in, u16* __restrict__ out,
                              int R, int Cc)
{
  __shared__ u16 t[32][33];
  const int bx = blockIdx.x * 32;
  const int by = blockIdx.y * 32;
  const int tx = threadIdx.x, ty = threadIdx.y;
#pragma unroll
  for (int i = ty; i < 32; i += 8)
    t[i][tx] = f2bf(in[(long)(by + i) * Cc + bx + tx]);
  __syncthreads();
#pragma unroll
  for (int i = ty; i < 32; i += 8)
    out[(long)(bx + i) * R + by + tx] = t[tx][i];
}

// 4x 256x256 fp32 weights -> bf16 NxK, z selects; z<3 packs into WqkvT.
__global__ void pack_w256(const float* __restrict__ w0, const float* __restrict__ w1,
                          const float* __restrict__ w2, const float* __restrict__ w3,
                          u16* __restrict__ qkvT, u16* __restrict__ wlT)
{
  __shared__ u16 t[32][33];
  const int z = blockIdx.z;
  const float* in = (z == 0) ? w0 : (z == 1) ? w1 : (z == 2) ? w2 : w3;
  u16* out = (z < 3) ? (qkvT + (long)z * C_ * C_) : wlT;
  const int bx = blockIdx.x * 32, by = blockIdx.y * 32;
  const int tx = threadIdx.x, ty = threadIdx.y;
#pragma unroll
  for (int i = ty; i < 32; i += 8)
    t[i][tx] = f2bf(in[(long)(by + i) * C_ + bx + tx]);
  __syncthreads();
#pragma unroll
  for (int i = ty; i < 32; i += 8)
    out[(long)(bx + i) * C_ + by + tx] = t[tx][i];
}

// fp32 -> bf16, z selects src/dst pair
__global__ void cast2_f2b(const float* __restrict__ in0, const float* __restrict__ in1,
                          u16* __restrict__ out0, u16* __restrict__ out1)
{
  const float* in = blockIdx.y ? in1 : in0;
  u16* out = blockIdx.y ? out1 : out0;
  int i = (blockIdx.x * 256 + threadIdx.x) * 4;
  float4 v = *(const float4*)(in + i);
  ushort4 o; o.x = f2bf(v.x); o.y = f2bf(v.y); o.z = f2bf(v.z); o.w = f2bf(v.w);
  *(ushort4*)(out + i) = o;
}

// ---------------------------------------------------------------------------
// In-place softmax over rows (length rowlen), bf16. One block per row.
// ---------------------------------------------------------------------------
__global__ void softmax_rows(u16* __restrict__ data, int rowlen)
{
  const long base = (long)blockIdx.x * rowlen;
  const int tid = threadIdx.x, wave = tid >> 6, lane = tid & 63;
  __shared__ float red[4];

  float m = -3.4e38f;
  for (int i = tid; i < rowlen; i += 256) m = fmaxf(m, bf2f(data[base + i]));
#pragma unroll
  for (int off = 32; off; off >>= 1) m = fmaxf(m, __shfl_xor(m, off, 64));
  if (lane == 0) red[wave] = m;
  __syncthreads();
  m = fmaxf(fmaxf(red[0], red[1]), fmaxf(red[2], red[3]));
  __syncthreads();

  float s = 0.f;
  for (int i = tid; i < rowlen; i += 256) s += expf(bf2f(data[base + i]) - m);
#pragma unroll
  for (int off = 32; off; off >>= 1) s += __shfl_xor(s, off, 64);
  if (lane == 0) red[wave] = s;
  __syncthreads();
  const float inv = 1.f / (red[0] + red[1] + red[2] + red[3]);
  for (int i = tid; i < rowlen; i += 256)
    data[base + i] = f2bf(expf(bf2f(data[base + i]) - m) * inv);
}

// ---------------------------------------------------------------------------
// LayerNorm rows of 256 (bf16 x, fp32 gamma/beta). OUTF=1: fp32 out + residual.
// ---------------------------------------------------------------------------
template<int OUTF>
__global__ void layernorm_rows(const u16* __restrict__ x,
                               const float* __restrict__ gamma,
                               const float* __restrict__ beta,
                               const float* __restrict__ src,
                               void* __restrict__ outv)
{
  const int wave = threadIdx.x >> 6, lane = threadIdx.x & 63;
  const long row = (long)blockIdx.x * 4 + wave;
  ushort4 raw = ((const ushort4*)(x + row * C_))[lane];
  float v0 = bf2f(raw.x), v1 = bf2f(raw.y), v2 = bf2f(raw.z), v3 = bf2f(raw.w);
  float s = v0 + v1 + v2 + v3;
  float q = v0 * v0 + v1 * v1 + v2 * v2 + v3 * v3;
#pragma unroll
  for (int off = 32; off; off >>= 1) {
    s += __shfl_xor(s, off, 64);
    q += __shfl_xor(q, off, 64);
  }
  const float mu  = s * (1.f / C_);
  const float var = q * (1.f / C_) - mu * mu;
  const float rs  = 1.f / sqrtf(var + EPS_);
  float4 gr = ((const float4*)gamma)[lane];
  float4 br = ((const float4*)beta)[lane];
  float o0 = (v0 - mu) * rs * gr.x + br.x;
  float o1 = (v1 - mu) * rs * gr.y + br.y;
  float o2 = (v2 - mu) * rs * gr.z + br.z;
  float o3 = (v3 - mu) * rs * gr.w + br.w;
  if (OUTF) {
    float4 sr = ((const float4*)(src + row * C_))[lane];
    float4 ow; ow.x = o0 + sr.x; ow.y = o1 + sr.y; ow.z = o2 + sr.z; ow.w = o3 + sr.w;
    ((float4*)((float*)outv + row * C_))[lane] = ow;
  } else {
    ushort4 ow; ow.x = f2bf(o0); ow.y = f2bf(o1); ow.z = f2bf(o2); ow.w = f2bf(o3);
    ((ushort4*)((u16*)outv + row * C_))[lane] = ow;
  }
}

__global__ void zero_f32(float* __restrict__ p, int n) {
  int i = blockIdx.x * 256 + threadIdx.x;
  if (i < n) p[i] = 0.f;
}
__global__ void f32_to_bf16_k(const float* __restrict__ in, u16* __restrict__ out, int n) {
  int i = blockIdx.x * 256 + threadIdx.x;
  if (i < n) out[i] = f2bf(in[i]);
}

// ---------------------------------------------------------------------------
extern "C" void kernel_launch(void* const* d_in, const int* in_sizes, int n_in,
                              void* d_out, int out_size, void* d_ws, size_t ws_size,
                              hipStream_t stream)
{
  const float* source = (const float*)d_in[0];
  const float* target = (const float*)d_in[1];
  const float* Wq     = (const float*)d_in[2];
  const float* Wk     = (const float*)d_in[3];
  const float* Wv     = (const float*)d_in[4];
  const float* Wl     = (const float*)d_in[5];
  const float* gamma1 = (const float*)d_in[6];
  const float* beta1  = (const float*)d_in[7];
  const float* W1     = (const float*)d_in[8];
  const float* b1     = (const float*)d_in[9];
  const float* W2     = (const float*)d_in[10];
  const float* b2     = (const float*)d_in[11];
  const float* gamma2 = (const float*)d_in[12];
  const float* beta2  = (const float*)d_in[13];
  (void)in_sizes; (void)n_in; (void)out_size;

  char* ws = (char*)d_ws;
  size_t off = 0;
  auto take = [&](size_t bytes) -> char* {
    char* p = ws + off; off += (bytes + 255) & ~(size_t)255; return p;
  };
  u16*   WqkvT = (u16*)take((size_t)768 * C_ * 2);
  u16*   WlT   = (u16*)take((size_t)C_ * C_ * 2);
  u16*   W1T   = (u16*)take((size_t)FFN_ * KCAT_ * 2);
  u16*   W2T   = (u16*)take((size_t)C_ * FFN_ * 2);
  float* ctxTf = (float*)take((size_t)B_ * C_ * C_ * 4);
  u16*   ctxTb = (u16*)take((size_t)B_ * C_ * C_ * 2);
  u16*   Mtb   = (u16*)take((size_t)B_ * C_ * C_ * 2);
  u16*   srcB  = (u16*)take((size_t)BLC_ * 2);   // bf16 source (lives to FFN1)
  u16*   bufB  = (u16*)take((size_t)BLC_ * 2);   // msg_pre
  u16*   bufD  = (u16*)take((size_t)BLC_ * 2);   // message
  u16*   bufE  = (u16*)take((size_t)BLC_ * 2);   // out_pre
  // union region: {tgtB, QKV, qT, kT} all dead before FFN1 writes hidden
  const size_t ubase = off;
  u16* tgtB = (u16*)(ws + ubase);
  u16* QKV  = (u16*)(ws + ubase + (size_t)BLC_ * 2);
  u16* qT   = (u16*)(ws + ubase + (size_t)BLC_ * 2 + (size_t)BL_ * 768 * 2);
  u16* kT   = qT + (size_t)BLC_;
  const size_t live = (size_t)BLC_ * 2 * 3 + (size_t)BL_ * 768 * 2;  // ~100.7 MB
  int nchunk = 1;
  while (nchunk < 16) {
    size_t hid = (size_t)(BL_ / nchunk) * FFN_ * 2;
    size_t need = ubase + (hid > live ? hid : live);
    if (need <= ws_size) break;
    nchunk <<= 1;
  }
  const int Mc = BL_ / nchunk;
  u16* hidden = (u16*)(ws + ubase);

  dim3 tb(32, 8);
  cast2_f2b<<<dim3(BLC_ / 1024, 2), 256, 0, stream>>>(source, target, srcB, tgtB);
  pack_w256<<<dim3(8, 8, 4), tb, 0, stream>>>(Wq, Wk, Wv, Wl, WqkvT, WlT);
  transpose_f2b<<<dim3(FFN_/32, KCAT_/32), tb, 0, stream>>>(W1, W1T, KCAT_, FFN_);
  transpose_f2b<<<dim3(C_/32,  FFN_/32), tb, 0, stream>>>(W2, W2T, FFN_, C_);
  zero_f32<<<(B_*C_*C_)/256, 256, 0, stream>>>(ctxTf, B_*C_*C_);

  // Fused QKV: [q|k|v] = [src|tgt|tgt] @ [Wq|Wk|Wv]   (N-switch at 256)
  gemm_abt<2,0,0><<<dim3((BL_/128)*(768/128)), 256, 0, stream>>>(
      srcB, tgtB, 256, C_, WqkvT, nullptr, QKV, nullptr, BL_, 768, C_, 0, 0, 0);

  // q,k -> (B, C, L); token-softmax = row softmax on kT
  transpose2d<<<dim3(C_/32, L_/32, B_), tb, 0, stream>>>(QKV,       qT, L_, C_, 768, (long)L_*768, (long)L_*C_);
  transpose2d<<<dim3(C_/32, L_/32, B_), tb, 0, stream>>>(QKV + 256, kT, L_, C_, 768, (long)L_*768, (long)L_*C_);
  softmax_rows<<<B_*C_, 256, 0, stream>>>(kT, L_);

  // ctxT[e,d] = sum_n ksm[n,e] q[n,d]  (split-K over tokens, fp32 atomics)
  gemm_abt<0,0,1><<<dim3(4, 16, B_), 256, 0, stream>>>(
      kT, kT, 0, L_, qT, nullptr, nullptr, ctxTf, C_, C_, L_,
      (long)C_*L_, (long)C_*L_, (long)C_*C_);
  f32_to_bf16_k<<<(B_*C_*C_)/256, 256, 0, stream>>>(ctxTf, ctxTb, B_*C_*C_);

  // Fold Wl: Mt[c,e] = sum_d WlT[c,d] * ctxT[e,d]   (tiny, batched, A shared)
  gemm_abt<0,0,0><<<dim3(4, 1, B_), 256, 0, stream>>>(
      WlT, WlT, 0, C_, ctxTb, nullptr, Mtb, nullptr, C_, C_, C_,
      0, (long)C_*C_, (long)C_*C_);

  // msg_pre[n,c] = sum_e v[n,e] * Mt[c,e]   (v strided inside QKV, lda=768)
  gemm_abt<0,0,0><<<dim3((L_/128)*(C_/128), 1, B_), 256, 0, stream>>>(
      QKV + 512, QKV + 512, 0, 768, Mtb, nullptr, bufB, nullptr, L_, C_, C_,
      (long)L_*768, (long)C_*C_, (long)L_*C_);

  // message = LN1(msg_pre)
  layernorm_rows<0><<<BL_/4, 256, 0, stream>>>(bufB, gamma1, beta1, nullptr, bufD);

  // FFN: hidden = gelu([src|msg]@W1+b1); out_pre = hidden@W2+b2
  for (int ch = 0; ch < nchunk; ch++) {
    const long moff = (long)ch * Mc;
    gemm_abt<1,1,0><<<dim3((Mc/128)*(FFN_/128)), 256, 0, stream>>>(
        srcB + moff * C_, bufD + moff * C_, C_, C_, W1T, b1, hidden, nullptr,
        Mc, FFN_, KCAT_, 0, 0, 0);
    gemm_abt<0,0,0><<<dim3((Mc/128)*(C_/128)), 256, 0, stream>>>(
        hidden, hidden, 0, FFN_, W2T, b2, bufE + moff * C_, nullptr,
        Mc, C_, FFN_, 0, 0, 0);
  }

  // out = source + LN2(out_pre)
  layernorm_rows<1><<<BL_/4, 256, 0, stream>>>(bufE, gamma2, beta2, source, d_out);
}